// Round 2
// baseline (376.962 us; speedup 1.0000x reference)
//
#include <hip/hip_runtime.h>

typedef __bf16 bf16_t;
typedef __bf16 bf16x4 __attribute__((ext_vector_type(4)));
typedef __bf16 bf16x8 __attribute__((ext_vector_type(8)));
typedef float f32x4 __attribute__((ext_vector_type(4)));

#define GLB(p) ((const __attribute__((address_space(1))) void*)(p))
#define LDS(p) ((__attribute__((address_space(3))) void*)(p))

// ---------------------------------------------------------------------------
// fp32 -> bf16 bulk convert (8 elems/thread, 16B stores)
// ---------------------------------------------------------------------------
__global__ void f32_to_bf16(const float* __restrict__ src, bf16_t* __restrict__ dst, int n8)
{
    const int i = blockIdx.x * 256 + threadIdx.x;
    if (i >= n8) return;
    const f32x4 a = *(const f32x4*)&src[(size_t)i * 8];
    const f32x4 b = *(const f32x4*)&src[(size_t)i * 8 + 4];
    bf16x8 h = {(bf16_t)a[0], (bf16_t)a[1], (bf16_t)a[2], (bf16_t)a[3],
                (bf16_t)b[0], (bf16_t)b[1], (bf16_t)b[2], (bf16_t)b[3]};
    *(bf16x8*)&dst[(size_t)i * 8] = h;
}

// ---------------------------------------------------------------------------
// 256x256 8-phase GEMM (HK-schedule port, plain HIP).
// BM=BN=256, BK=64, 512 thr (8 waves, 2Mx4N), per-wave C = 128x64.
// LDS 128 KiB: 2 bufs x { A[2][256][32] , B[2][256][32] } (K-split halves),
// XOR col-swizzle (pre-swizzled global source, linear global_load_lds dest,
// swizzled ds_read).  Counted vmcnt(6): 3 half-tiles always in flight.
// Half-tile ids per K-tile: h0=B_k0, h1=A_k0, h2=B_k1, h3=A_k1.
// Iter J (tiles t=2J in buf0 ph1-4, t+1 in buf1 ph5-8) stages:
//   ph1:(t+1)h3  ph2:(t+2)h0  ph3:(t+2)h1  ph4:(t+2)h2+vmcnt(6)
//   ph5:(t+2)h3  ph6:(t+3)h0  ph7:(t+3)h1  ph8:(t+3)h2+vmcnt(6)
// Read deadlines verified: region ds_reads finish >=1 barrier before its
// overwrite; each vmcnt(6) leaves exactly the 3 newest half-tiles in flight.
// MODE 0: scatter -> q/k (B,H,T,hd), vT (B,H,hd,T).  MODE 1: fp32 store.
// ---------------------------------------------------------------------------
#define LDB4(d, kk)                                                            \
    { _Pragma("unroll") for (int nt = 0; nt < 4; ++nt)                         \
        bfr[nt] = *(const bf16x8*)(sBb + (d) * 65536 + (kk) * 16384 + nt * 1024); }

#define LDA4(d, kk, g)                                                         \
    { _Pragma("unroll") for (int i = 0; i < 4; ++i)                            \
        afr[i] = *(const bf16x8*)(sAb + (d) * 65536 + (kk) * 16384 + ((g) * 4 + i) * 1024); }

#define MM4(g)                                                                 \
    { _Pragma("unroll") for (int i = 0; i < 4; ++i)                            \
        _Pragma("unroll") for (int nt = 0; nt < 4; ++nt)                       \
            acc[(g) * 4 + i][nt] = __builtin_amdgcn_mfma_f32_16x16x32_bf16(    \
                afr[i], bfr[nt], acc[(g) * 4 + i][nt], 0, 0, 0); }

#define PHASE_TAIL(g)                                                          \
    __builtin_amdgcn_s_barrier();                                              \
    asm volatile("s_waitcnt lgkmcnt(0)" ::: "memory");                         \
    __builtin_amdgcn_s_setprio(1);                                             \
    MM4(g);                                                                    \
    __builtin_amdgcn_s_setprio(0);                                             \
    __builtin_amdgcn_s_barrier();

template <int MODE>
__global__ __launch_bounds__(512, 2)
void gemm256(const bf16_t* __restrict__ A, const bf16_t* __restrict__ Bm, int K,
             bf16_t* __restrict__ o0, bf16_t* __restrict__ o1, bf16_t* __restrict__ o2,
             float* __restrict__ of)
{
    __shared__ __align__(16) bf16_t smem[65536];   // 128 KiB
    char* smbase = (char*)smem;

    const int tid  = threadIdx.x;
    const int lane = tid & 63;
    const int w    = tid >> 6;
    const int wr   = w >> 2;       // 0..1  (M rows of waves)
    const int wc   = w & 3;        // 0..3  (N cols of waves)
    const int quad = lane >> 4;
    const int qcol = lane & 15;
    const int m0   = blockIdx.x * 256;
    const int n0   = blockIdx.y * 256;

    f32x4 acc[8][4];
#pragma unroll
    for (int i = 0; i < 8; ++i)
#pragma unroll
        for (int j = 0; j < 4; ++j)
            acc[i][j] = (f32x4){0.f, 0.f, 0.f, 0.f};

    // ---- staging geometry: half-tile = 256 rows x 32 k-cols (16 KiB) ----
    // thread covers row = w*16 + (lane>>2) (+128 for 2nd load), 16B col-group
    // pre-swizzled on the GLOBAL side: cg = (lane&3) ^ ((lane>>2)&3).
    const int srow = w * 16 + (lane >> 2);
    const int scg  = (lane & 3) ^ ((lane >> 2) & 3);
    const bf16_t* Ag = A  + (size_t)(m0 + srow) * K + scg * 8;
    const bf16_t* Bg = Bm + (size_t)(n0 + srow) * K + scg * 8;

    auto STAGE = [&](int d, int t, int hh) {
        const int isA = hh & 1;
        const int kh  = hh >> 1;
        const bf16_t* g = (isA ? Ag : Bg) + t * 64 + kh * 32;
        char* l = smbase + d * 65536 + kh * 16384 + (isA ? 0 : 32768) + w * 1024;
        __builtin_amdgcn_global_load_lds(GLB(g), LDS(l), 16, 0, 0);
        __builtin_amdgcn_global_load_lds(GLB(g + (size_t)128 * K), LDS(l + 8192), 16, 0, 0);
    };

    // ---- read bases (swizzled): row stride 64 B, row&3 == qcol&3 ----
    const int rswz = (quad ^ (qcol & 3)) << 4;
    const char* sAb = smbase + (wr * 128 + qcol) * 64 + rswz;
    const char* sBb = smbase + 32768 + (wc * 64 + qcol) * 64 + rswz;

    bf16x8 afr[4], bfr[4];

    const int NT  = K >> 6;    // K-tiles of 64
    const int NIT = NT >> 1;   // 2 tiles per iteration

    // ---- prologue: tile0 fully staged, tile1 h0-h2 in flight ----
    STAGE(0, 0, 0); STAGE(0, 0, 1); STAGE(0, 0, 2); STAGE(0, 0, 3);
    STAGE(1, 1, 0); STAGE(1, 1, 1); STAGE(1, 1, 2);
    asm volatile("s_waitcnt vmcnt(6)" ::: "memory");
    __builtin_amdgcn_s_barrier();

    for (int J = 0; J < NIT - 1; ++J) {
        const int t = 2 * J;
        // ph1
        LDB4(0, 0); LDA4(0, 0, 0); STAGE(1, t + 1, 3);
        PHASE_TAIL(0);
        // ph2
        LDA4(0, 0, 1); STAGE(0, t + 2, 0);
        PHASE_TAIL(1);
        // ph3
        LDB4(0, 1); LDA4(0, 1, 0); STAGE(0, t + 2, 1);
        PHASE_TAIL(0);
        // ph4
        LDA4(0, 1, 1); STAGE(0, t + 2, 2);
        asm volatile("s_waitcnt vmcnt(6)" ::: "memory");
        PHASE_TAIL(1);
        // ph5
        LDB4(1, 0); LDA4(1, 0, 0); STAGE(0, t + 2, 3);
        PHASE_TAIL(0);
        // ph6
        LDA4(1, 0, 1); STAGE(1, t + 3, 0);
        PHASE_TAIL(1);
        // ph7
        LDB4(1, 1); LDA4(1, 1, 0); STAGE(1, t + 3, 1);
        PHASE_TAIL(0);
        // ph8
        LDA4(1, 1, 1); STAGE(1, t + 3, 2);
        asm volatile("s_waitcnt vmcnt(6)" ::: "memory");
        PHASE_TAIL(1);
    }

    // ---- final iteration (tiles NT-2, NT-1): drain ----
    {
        const int t = NT - 2;
        LDB4(0, 0); LDA4(0, 0, 0); STAGE(1, t + 1, 3);
        PHASE_TAIL(0);
        LDA4(0, 0, 1);
        PHASE_TAIL(1);
        LDB4(0, 1); LDA4(0, 1, 0);
        PHASE_TAIL(0);
        LDA4(0, 1, 1);
        asm volatile("s_waitcnt vmcnt(0)" ::: "memory");
        PHASE_TAIL(1);
        LDB4(1, 0); LDA4(1, 0, 0);
        PHASE_TAIL(0);
        LDA4(1, 0, 1);
        PHASE_TAIL(1);
        LDB4(1, 1); LDA4(1, 1, 0);
        PHASE_TAIL(0);
        LDA4(1, 1, 1);
        __builtin_amdgcn_s_barrier();
        asm volatile("s_waitcnt lgkmcnt(0)" ::: "memory");
        __builtin_amdgcn_s_setprio(1);
        MM4(1);
        __builtin_amdgcn_s_setprio(0);
    }

    // ---- epilogue ----
#pragma unroll
    for (int mt = 0; mt < 8; ++mt) {
#pragma unroll
        for (int nt = 0; nt < 4; ++nt) {
#pragma unroll
            for (int r = 0; r < 4; ++r) {
                const int m = m0 + wr * 128 + mt * 16 + quad * 4 + r;
                const int f = n0 + wc * 64 + nt * 16 + qcol;
                const float val = acc[mt][nt][r];
                if (MODE == 0) {
                    const int b     = m >> 9;          // T = 512
                    const int t     = m & 511;
                    const int which = f >> 11;
                    const int h     = (f >> 7) & 15;
                    const int d     = f & 127;
                    if (which == 2) {
                        o2[((size_t)(((b << 4) + h) * 128 + d) << 9) + t] = (bf16_t)val;
                    } else {
                        bf16_t* dst = (which == 0) ? o0 : o1;
                        dst[(size_t)(((b << 4) + h) * 512 + t) * 128 + d] = (bf16_t)val;
                    }
                } else {
                    of[(size_t)m * 2048 + f] = val;
                }
            }
        }
    }
}

// ---------------------------------------------------------------------------
// RoPE (in-place on bf16 q and k; v untouched)
// ---------------------------------------------------------------------------
__global__ void rope_kernel(bf16_t* __restrict__ q, bf16_t* __restrict__ k)
{
    const int id  = blockIdx.x * 256 + threadIdx.x;
    const int arr = id >> 19;
    const int rem = id & ((1 << 19) - 1);
    const int bh  = rem >> 12;
    const int t   = (rem >> 3) & 511;
    const int d   = rem & 7;

    bf16_t* p = (arr ? k : q) + (size_t)(bh * 512 + t) * 128;
    const float x1 = (float)p[d];
    const float x2 = (float)p[d + 8];
    const float freq = __expf(-(float)d * 1.1512925464970229f);  // ln(10000)/8
    const float ang  = (float)t * freq;
    const float c = cosf(ang), s = sinf(ang);
    p[d]     = (bf16_t)(x1 * c - x2 * s);
    p[d + 8] = (bf16_t)(x2 * c + x1 * s);
}

// ---------------------------------------------------------------------------
// MFMA flash attention, BQ=128, BK=64. Block = 256 thr (4 waves) per
// (b, h, 128-query tile). Wave w owns 32 queries (2 x 16-query groups qg).
// S^T = K·Q^T (query = lane&15 per qg); shfl softmax; P via wave-private LDS;
// O += P·V with V^T staged from (B,H,hd,T) global.
// ---------------------------------------------------------------------------
#define KLD 136
#define VLD 72
#define PLD 72

__global__ __launch_bounds__(256)
void flash_attn(const bf16_t* __restrict__ q, const bf16_t* __restrict__ k,
                const bf16_t* __restrict__ vT, bf16_t* __restrict__ y)
{
    const int qtb = blockIdx.x;   // 0..3 (128-query tiles)
    const int h   = blockIdx.y;
    const int b   = blockIdx.z;
    const int tid  = threadIdx.x;
    const int lane = tid & 63;
    const int w    = tid >> 6;
    const int quad = lane >> 4;
    const int qcol = lane & 15;

    __shared__ __align__(16) bf16_t Ks[64 * KLD];      // keys x dims
    __shared__ __align__(16) bf16_t VTs[128 * VLD];    // dims x keys
    __shared__ __align__(16) bf16_t Ps[128 * PLD];     // queries x keys
    __shared__ __align__(16) float aS[4][2][16];
    __shared__ __align__(16) float lS[4][2][16];

    const bf16_t* qb  = q  + (size_t)((b * 16 + h) * 512) * 128;
    const bf16_t* kb  = k  + (size_t)((b * 16 + h) * 512) * 128;
    const bf16_t* vtb = vT + (size_t)((b * 16 + h) * 128) * 512;

    // Q fragments (B-operand): query = qtb*128 + w*32 + qg*16 + qcol
    bf16x8 qfrag[2][4];
#pragma unroll
    for (int qg = 0; qg < 2; ++qg) {
        const int qrow = qtb * 128 + w * 32 + qg * 16 + qcol;
#pragma unroll
        for (int kc = 0; kc < 4; ++kc)
            qfrag[qg][kc] = *(const bf16x8*)&qb[(size_t)qrow * 128 + kc * 32 + quad * 8];
    }

    f32x4 acc_o[2][8];
#pragma unroll
    for (int qg = 0; qg < 2; ++qg)
#pragma unroll
        for (int nt = 0; nt < 8; ++nt) acc_o[qg][nt] = (f32x4){0.f, 0.f, 0.f, 0.f};
    float m_run[2] = {-INFINITY, -INFINITY};
    float l_run[2] = {0.f, 0.f};
    const float scale = 0.08838834764831845f;   // 1/sqrt(128)

    const int kt_last = 2 * qtb + 1;
    for (int kt = 0; kt <= kt_last; ++kt) {
        __syncthreads();
        // stage K tile (64 keys x 128 dims)
#pragma unroll
        for (int p = 0; p < 4; ++p) {
            const int r = p * 16 + (tid >> 4), c = (tid & 15) * 8;
            *(uint4*)&Ks[r * KLD + c] = *(const uint4*)&kb[(size_t)(kt * 64 + r) * 128 + c];
        }
        // stage V^T tile (128 dims x 64 keys)
#pragma unroll
        for (int p = 0; p < 4; ++p) {
            const int r = p * 32 + (tid >> 3), c = (tid & 7) * 8;
            *(uint4*)&VTs[r * VLD + c] = *(const uint4*)&vtb[(size_t)r * 512 + kt * 64 + c];
        }
        __syncthreads();

        const bool need_mask = (kt >= 2 * qtb);

#pragma unroll
        for (int qg = 0; qg < 2; ++qg) {
            // S^T (M=64 keys, N=16 queries, K=128): 16 MFMA
            f32x4 sacc[4];
#pragma unroll
            for (int mt = 0; mt < 4; ++mt) sacc[mt] = (f32x4){0.f, 0.f, 0.f, 0.f};
#pragma unroll
            for (int mt = 0; mt < 4; ++mt)
#pragma unroll
                for (int kc = 0; kc < 4; ++kc) {
                    bf16x8 af = *(const bf16x8*)&Ks[(mt * 16 + qcol) * KLD + kc * 32 + quad * 8];
                    sacc[mt] = __builtin_amdgcn_mfma_f32_16x16x32_bf16(af, qfrag[qg][kc], sacc[mt], 0, 0, 0);
                }

            float s[16];
#pragma unroll
            for (int mt = 0; mt < 4; ++mt)
#pragma unroll
                for (int r = 0; r < 4; ++r)
                    s[mt * 4 + r] = sacc[mt][r] * scale;
            if (need_mask) {
                const int qglob = qtb * 128 + w * 32 + qg * 16 + qcol;
#pragma unroll
                for (int mt = 0; mt < 4; ++mt)
#pragma unroll
                    for (int r = 0; r < 4; ++r)
                        if (kt * 64 + mt * 16 + quad * 4 + r > qglob)
                            s[mt * 4 + r] = -1e30f;
            }

            float mx = s[0];
#pragma unroll
            for (int i = 1; i < 16; ++i) mx = fmaxf(mx, s[i]);
            mx = fmaxf(mx, __shfl_xor(mx, 16));
            mx = fmaxf(mx, __shfl_xor(mx, 32));
            const float m_new = fmaxf(m_run[qg], mx);
            const float alpha = __expf(m_run[qg] - m_new);   // first iter: exp(-inf)=0
            float p16[16];
            float sum = 0.f;
#pragma unroll
            for (int i = 0; i < 16; ++i) { p16[i] = __expf(s[i] - m_new); sum += p16[i]; }
            sum += __shfl_xor(sum, 16);
            sum += __shfl_xor(sum, 32);
            l_run[qg] = l_run[qg] * alpha + sum;
            m_run[qg] = m_new;
            if (quad == 0) aS[w][qg][qcol] = alpha;

            // P -> wave-private LDS rows [w*32 + qg*16, +16)
#pragma unroll
            for (int mt = 0; mt < 4; ++mt) {
                bf16x4 pb = {(bf16_t)p16[mt * 4 + 0], (bf16_t)p16[mt * 4 + 1],
                             (bf16_t)p16[mt * 4 + 2], (bf16_t)p16[mt * 4 + 3]};
                *(bf16x4*)&Ps[(w * 32 + qg * 16 + qcol) * PLD + mt * 16 + quad * 4] = pb;
            }

            // rescale O rows (query = quad*4 + r within qg) by alpha
            f32x4 alpha4 = *(const f32x4*)&aS[w][qg][quad * 4];
#pragma unroll
            for (int nt = 0; nt < 8; ++nt)
#pragma unroll
                for (int r = 0; r < 4; ++r)
                    acc_o[qg][nt][r] *= alpha4[r];

            // O += P·V (M=16 queries, N=128 dims, K=64 keys): 16 MFMA
#pragma unroll
            for (int kc2 = 0; kc2 < 2; ++kc2) {
                bf16x8 pf = *(const bf16x8*)&Ps[(w * 32 + qg * 16 + qcol) * PLD + kc2 * 32 + quad * 8];
#pragma unroll
                for (int nt = 0; nt < 8; ++nt) {
                    bf16x8 vf = *(const bf16x8*)&VTs[(nt * 16 + qcol) * VLD + kc2 * 32 + quad * 8];
                    acc_o[qg][nt] = __builtin_amdgcn_mfma_f32_16x16x32_bf16(pf, vf, acc_o[qg][nt], 0, 0, 0);
                }
            }
        }
    }

    // epilogue: y[(b, t, h*128 + d)] = O / l
    if (quad == 0) { lS[w][0][qcol] = l_run[0]; lS[w][1][qcol] = l_run[1]; }
#pragma unroll
    for (int qg = 0; qg < 2; ++qg) {
        f32x4 l4 = *(const f32x4*)&lS[w][qg][quad * 4];
#pragma unroll
        for (int nt = 0; nt < 8; ++nt)
#pragma unroll
            for (int r = 0; r < 4; ++r) {
                const int t  = qtb * 128 + w * 32 + qg * 16 + quad * 4 + r;
                const int cc = h * 128 + nt * 16 + qcol;
                y[(size_t)(b * 512 + t) * 2048 + cc] = (bf16_t)(acc_o[qg][nt][r] / l4[r]);
            }
    }
}

// ---------------------------------------------------------------------------
extern "C" void kernel_launch(void* const* d_in, const int* in_sizes, int n_in,
                              void* d_out, int out_size, void* d_ws, size_t ws_size,
                              hipStream_t stream)
{
    (void)in_sizes; (void)n_in; (void)out_size; (void)ws_size;

    const float* x    = (const float*)d_in[0];   // (8, 512, 2048) fp32
    const float* Wqkv = (const float*)d_in[1];   // (6144, 2048)  fp32
    const float* Wout = (const float*)d_in[2];   // (2048, 2048)  fp32
    float* out = (float*)d_out;                  // (8, 512, 2048) fp32

    const size_t SEG = (size_t)8 * 16 * 512 * 128;   // 8,388,608 elems (16 MB bf16)
    bf16_t* q      = (bf16_t*)d_ws;          // [0, 16 MB)
    bf16_t* k      = q + SEG;                // [16, 32)
    bf16_t* vT     = k + SEG;                // [32, 48)   (B,H,hd,T)
    bf16_t* xb     = vT + SEG;               // [48, 64)   bf16 x — dead after GEMM1
    bf16_t* y      = xb;                     //            y aliases xb
    bf16_t* Wqkvb  = xb + SEG;               // [64, 88)   bf16 Wqkv
    bf16_t* Woutb  = Wqkvb + (size_t)6144 * 2048;   // [88, 96)

    f32_to_bf16<<<(8388608 / 8) / 256, 256, 0, stream>>>(x, xb, 8388608 / 8);
    f32_to_bf16<<<(12582912 / 8) / 256, 256, 0, stream>>>(Wqkv, Wqkvb, 12582912 / 8);
    f32_to_bf16<<<(4194304 / 8) / 256, 256, 0, stream>>>(Wout, Woutb, 4194304 / 8);
    gemm256<0><<<dim3(4096 / 256, 6144 / 256), 512, 0, stream>>>(xb, Wqkvb, 2048, q, k, vT, nullptr);
    rope_kernel<<<(2 * 128 * 512 * 8) / 256, 256, 0, stream>>>(q, k);
    flash_attn<<<dim3(4, 16, 8), 256, 0, stream>>>(q, k, vT, y);
    gemm256<1><<<dim3(4096 / 256, 2048 / 256), 512, 0, stream>>>(y, Woutb, 2048, nullptr, nullptr, nullptr, out);
}

// Round 3
// 364.344 us; speedup vs baseline: 1.0346x; 1.0346x over previous
//
#include <hip/hip_runtime.h>

typedef __bf16 bf16_t;
typedef __bf16 bf16x4 __attribute__((ext_vector_type(4)));
typedef __bf16 bf16x8 __attribute__((ext_vector_type(8)));
typedef float f32x4 __attribute__((ext_vector_type(4)));

#define GLB(p) ((const __attribute__((address_space(1))) void*)(p))
#define LDS(p) ((__attribute__((address_space(3))) void*)(p))

// ---------------------------------------------------------------------------
// fp32 -> bf16 bulk convert (8 elems/thread, 16B stores)
// ---------------------------------------------------------------------------
__global__ void f32_to_bf16(const float* __restrict__ src, bf16_t* __restrict__ dst, int n8)
{
    const int i = blockIdx.x * 256 + threadIdx.x;
    if (i >= n8) return;
    const f32x4 a = *(const f32x4*)&src[(size_t)i * 8];
    const f32x4 b = *(const f32x4*)&src[(size_t)i * 8 + 4];
    bf16x8 h = {(bf16_t)a[0], (bf16_t)a[1], (bf16_t)a[2], (bf16_t)a[3],
                (bf16_t)b[0], (bf16_t)b[1], (bf16_t)b[2], (bf16_t)b[3]};
    *(bf16x8*)&dst[(size_t)i * 8] = h;
}

// ---------------------------------------------------------------------------
// 256x256 8-phase GEMM (HK-schedule port, plain HIP).
// BM=BN=256, BK=64, 512 thr (8 waves, 2Mx4N), per-wave C = 128x64.
// LDS 128 KiB (in bf16 ELEMENT units, 65536 elems):
//   [d]*32768 + [kh]*8192 + (A:0 | B:16384) + row*32 + slot*8
// Half-tile = 256 rows x 32 k-cols (8192 elems).  XOR swizzle: position p of
// row r holds col-group p ^ ((r>>1)&3)  (pre-swizzled global source, linear
// global_load_lds dest, swizzled ds_read -> conflict-free b128 reads).
// ALL LDS accesses via typed element-indexing of __shared__ smem[] so the
// compiler emits ds_read_b128 (generic char* math risked flat_load, which
// pollutes vmcnt and destroys the counted-vmcnt schedule).
// Counted vmcnt(6): 3 half-tiles always in flight.
// Half-tile ids per K-tile: h0=B_k0, h1=A_k0, h2=B_k1, h3=A_k1.
// Iter J (tiles t=2J in buf0 ph1-4, t+1 in buf1 ph5-8) stages:
//   ph1:(t+1)h3  ph2:(t+2)h0  ph3:(t+2)h1  ph4:(t+2)h2+vmcnt(6)
//   ph5:(t+2)h3  ph6:(t+3)h0  ph7:(t+3)h1  ph8:(t+3)h2+vmcnt(6)
// MODE 0: scatter -> q/k (B,H,T,hd), vT (B,H,hd,T).  MODE 1: fp32 store.
// ---------------------------------------------------------------------------
#define LDB4(d, kk)                                                            \
    { _Pragma("unroll") for (int nt = 0; nt < 4; ++nt)                         \
        bfr[nt] = *(const bf16x8*)&smem[sBe + (d) * 32768 + (kk) * 8192 + nt * 512]; }

#define LDA4(d, kk, g)                                                         \
    { _Pragma("unroll") for (int i = 0; i < 4; ++i)                            \
        afr[i] = *(const bf16x8*)&smem[sAe + (d) * 32768 + (kk) * 8192 + ((g) * 4 + i) * 512]; }

#define MM4(g)                                                                 \
    { _Pragma("unroll") for (int i = 0; i < 4; ++i)                            \
        _Pragma("unroll") for (int nt = 0; nt < 4; ++nt)                       \
            acc[(g) * 4 + i][nt] = __builtin_amdgcn_mfma_f32_16x16x32_bf16(    \
                afr[i], bfr[nt], acc[(g) * 4 + i][nt], 0, 0, 0); }

#define PHASE_TAIL(g)                                                          \
    __builtin_amdgcn_s_barrier();                                              \
    asm volatile("s_waitcnt lgkmcnt(0)" ::: "memory");                         \
    __builtin_amdgcn_s_setprio(1);                                             \
    MM4(g);                                                                    \
    __builtin_amdgcn_s_setprio(0);                                             \
    __builtin_amdgcn_s_barrier();

template <int MODE>
__global__ __launch_bounds__(512, 2)
void gemm256(const bf16_t* __restrict__ A, const bf16_t* __restrict__ Bm, int K,
             bf16_t* __restrict__ o0, bf16_t* __restrict__ o1, bf16_t* __restrict__ o2,
             float* __restrict__ of)
{
    __shared__ __align__(16) bf16_t smem[65536];   // 128 KiB

    const int tid  = threadIdx.x;
    const int lane = tid & 63;
    const int w    = tid >> 6;
    const int wr   = w >> 2;       // 0..1  (M rows of waves)
    const int wc   = w & 3;        // 0..3  (N cols of waves)
    const int quad = lane >> 4;
    const int qcol = lane & 15;
    const int m0   = blockIdx.x * 256;
    const int n0   = blockIdx.y * 256;

    f32x4 acc[8][4];
#pragma unroll
    for (int i = 0; i < 8; ++i)
#pragma unroll
        for (int j = 0; j < 4; ++j)
            acc[i][j] = (f32x4){0.f, 0.f, 0.f, 0.f};

    // ---- staging geometry: half-tile = 256 rows x 32 k-cols ----
    // thread covers row = w*16 + (lane>>2) (+128 for 2nd load); global col
    // group pre-swizzled: scg = (lane&3) ^ ((lane>>3)&3)  [= (row>>1)&3].
    const int srow = w * 16 + (lane >> 2);
    const int scg  = (lane & 3) ^ ((lane >> 3) & 3);
    const bf16_t* Ag = A  + (size_t)(m0 + srow) * K + scg * 8;
    const bf16_t* Bg = Bm + (size_t)(n0 + srow) * K + scg * 8;

    auto STAGE = [&](int d, int t, int hh) {
        const int isA = hh & 1;
        const int kh  = hh >> 1;
        const bf16_t* g = (isA ? Ag : Bg) + t * 64 + kh * 32;
        bf16_t* l = &smem[d * 32768 + kh * 8192 + (isA ? 0 : 16384) + w * 512];
        __builtin_amdgcn_global_load_lds(GLB(g), LDS(l), 16, 0, 0);
        __builtin_amdgcn_global_load_lds(GLB(g + (size_t)128 * K), LDS(l + 4096), 16, 0, 0);
    };

    // ---- read bases (element units): row*32 + slot*8, slot = quad^((row>>1)&3)
    const int rs8 = (quad ^ ((qcol >> 1) & 3)) * 8;
    const int sAe = (wr * 128 + qcol) * 32 + rs8;
    const int sBe = 16384 + (wc * 64 + qcol) * 32 + rs8;

    bf16x8 afr[4], bfr[4];

    const int NT  = K >> 6;    // K-tiles of 64
    const int NIT = NT >> 1;   // 2 tiles per iteration

    // ---- prologue: tile0 fully staged, tile1 h0-h2 in flight ----
    STAGE(0, 0, 0); STAGE(0, 0, 1); STAGE(0, 0, 2); STAGE(0, 0, 3);
    STAGE(1, 1, 0); STAGE(1, 1, 1); STAGE(1, 1, 2);
    asm volatile("s_waitcnt vmcnt(6)" ::: "memory");
    __builtin_amdgcn_s_barrier();

    for (int J = 0; J < NIT - 1; ++J) {
        const int t = 2 * J;
        // ph1
        LDB4(0, 0); LDA4(0, 0, 0); STAGE(1, t + 1, 3);
        PHASE_TAIL(0);
        // ph2
        LDA4(0, 0, 1); STAGE(0, t + 2, 0);
        PHASE_TAIL(1);
        // ph3
        LDB4(0, 1); LDA4(0, 1, 0); STAGE(0, t + 2, 1);
        PHASE_TAIL(0);
        // ph4
        LDA4(0, 1, 1); STAGE(0, t + 2, 2);
        asm volatile("s_waitcnt vmcnt(6)" ::: "memory");
        PHASE_TAIL(1);
        // ph5
        LDB4(1, 0); LDA4(1, 0, 0); STAGE(0, t + 2, 3);
        PHASE_TAIL(0);
        // ph6
        LDA4(1, 0, 1); STAGE(1, t + 3, 0);
        PHASE_TAIL(1);
        // ph7
        LDB4(1, 1); LDA4(1, 1, 0); STAGE(1, t + 3, 1);
        PHASE_TAIL(0);
        // ph8
        LDA4(1, 1, 1); STAGE(1, t + 3, 2);
        asm volatile("s_waitcnt vmcnt(6)" ::: "memory");
        PHASE_TAIL(1);
    }

    // ---- final iteration (tiles NT-2, NT-1): drain ----
    {
        const int t = NT - 2;
        LDB4(0, 0); LDA4(0, 0, 0); STAGE(1, t + 1, 3);
        PHASE_TAIL(0);
        LDA4(0, 0, 1);
        PHASE_TAIL(1);
        LDB4(0, 1); LDA4(0, 1, 0);
        PHASE_TAIL(0);
        LDA4(0, 1, 1);
        asm volatile("s_waitcnt vmcnt(0)" ::: "memory");
        PHASE_TAIL(1);
        LDB4(1, 0); LDA4(1, 0, 0);
        PHASE_TAIL(0);
        LDA4(1, 0, 1);
        PHASE_TAIL(1);
        LDB4(1, 1); LDA4(1, 1, 0);
        PHASE_TAIL(0);
        LDA4(1, 1, 1);
        __builtin_amdgcn_s_barrier();
        asm volatile("s_waitcnt lgkmcnt(0)" ::: "memory");
        __builtin_amdgcn_s_setprio(1);
        MM4(1);
        __builtin_amdgcn_s_setprio(0);
    }

    // ---- epilogue ----
#pragma unroll
    for (int mt = 0; mt < 8; ++mt) {
#pragma unroll
        for (int nt = 0; nt < 4; ++nt) {
#pragma unroll
            for (int r = 0; r < 4; ++r) {
                const int m = m0 + wr * 128 + mt * 16 + quad * 4 + r;
                const int f = n0 + wc * 64 + nt * 16 + qcol;
                const float val = acc[mt][nt][r];
                if (MODE == 0) {
                    const int b     = m >> 9;          // T = 512
                    const int t     = m & 511;
                    const int which = f >> 11;
                    const int h     = (f >> 7) & 15;
                    const int d     = f & 127;
                    if (which == 2) {
                        o2[((size_t)(((b << 4) + h) * 128 + d) << 9) + t] = (bf16_t)val;
                    } else {
                        bf16_t* dst = (which == 0) ? o0 : o1;
                        dst[(size_t)(((b << 4) + h) * 512 + t) * 128 + d] = (bf16_t)val;
                    }
                } else {
                    of[(size_t)m * 2048 + f] = val;
                }
            }
        }
    }
}

// ---------------------------------------------------------------------------
// RoPE (in-place on bf16 q and k; v untouched)
// ---------------------------------------------------------------------------
__global__ void rope_kernel(bf16_t* __restrict__ q, bf16_t* __restrict__ k)
{
    const int id  = blockIdx.x * 256 + threadIdx.x;
    const int arr = id >> 19;
    const int rem = id & ((1 << 19) - 1);
    const int bh  = rem >> 12;
    const int t   = (rem >> 3) & 511;
    const int d   = rem & 7;

    bf16_t* p = (arr ? k : q) + (size_t)(bh * 512 + t) * 128;
    const float x1 = (float)p[d];
    const float x2 = (float)p[d + 8];
    const float freq = __expf(-(float)d * 1.1512925464970229f);  // ln(10000)/8
    const float ang  = (float)t * freq;
    const float c = cosf(ang), s = sinf(ang);
    p[d]     = (bf16_t)(x1 * c - x2 * s);
    p[d + 8] = (bf16_t)(x2 * c + x1 * s);
}

// ---------------------------------------------------------------------------
// MFMA flash attention, BQ=128, BK=64. Block = 256 thr (4 waves) per
// (b, h, 128-query tile). Wave w owns 32 queries (2 x 16-query groups qg).
// S^T = K·Q^T (query = lane&15 per qg); shfl softmax; P via wave-private LDS;
// O += P·V with V^T staged from (B,H,hd,T) global.
// ---------------------------------------------------------------------------
#define KLD 136
#define VLD 72
#define PLD 72

__global__ __launch_bounds__(256)
void flash_attn(const bf16_t* __restrict__ q, const bf16_t* __restrict__ k,
                const bf16_t* __restrict__ vT, bf16_t* __restrict__ y)
{
    const int qtb = blockIdx.x;   // 0..3 (128-query tiles)
    const int h   = blockIdx.y;
    const int b   = blockIdx.z;
    const int tid  = threadIdx.x;
    const int lane = tid & 63;
    const int w    = tid >> 6;
    const int quad = lane >> 4;
    const int qcol = lane & 15;

    __shared__ __align__(16) bf16_t Ks[64 * KLD];      // keys x dims
    __shared__ __align__(16) bf16_t VTs[128 * VLD];    // dims x keys
    __shared__ __align__(16) bf16_t Ps[128 * PLD];     // queries x keys
    __shared__ __align__(16) float aS[4][2][16];
    __shared__ __align__(16) float lS[4][2][16];

    const bf16_t* qb  = q  + (size_t)((b * 16 + h) * 512) * 128;
    const bf16_t* kb  = k  + (size_t)((b * 16 + h) * 512) * 128;
    const bf16_t* vtb = vT + (size_t)((b * 16 + h) * 128) * 512;

    // Q fragments (B-operand): query = qtb*128 + w*32 + qg*16 + qcol
    bf16x8 qfrag[2][4];
#pragma unroll
    for (int qg = 0; qg < 2; ++qg) {
        const int qrow = qtb * 128 + w * 32 + qg * 16 + qcol;
#pragma unroll
        for (int kc = 0; kc < 4; ++kc)
            qfrag[qg][kc] = *(const bf16x8*)&qb[(size_t)qrow * 128 + kc * 32 + quad * 8];
    }

    f32x4 acc_o[2][8];
#pragma unroll
    for (int qg = 0; qg < 2; ++qg)
#pragma unroll
        for (int nt = 0; nt < 8; ++nt) acc_o[qg][nt] = (f32x4){0.f, 0.f, 0.f, 0.f};
    float m_run[2] = {-INFINITY, -INFINITY};
    float l_run[2] = {0.f, 0.f};
    const float scale = 0.08838834764831845f;   // 1/sqrt(128)

    const int kt_last = 2 * qtb + 1;
    for (int kt = 0; kt <= kt_last; ++kt) {
        __syncthreads();
        // stage K tile (64 keys x 128 dims)
#pragma unroll
        for (int p = 0; p < 4; ++p) {
            const int r = p * 16 + (tid >> 4), c = (tid & 15) * 8;
            *(uint4*)&Ks[r * KLD + c] = *(const uint4*)&kb[(size_t)(kt * 64 + r) * 128 + c];
        }
        // stage V^T tile (128 dims x 64 keys)
#pragma unroll
        for (int p = 0; p < 4; ++p) {
            const int r = p * 32 + (tid >> 3), c = (tid & 7) * 8;
            *(uint4*)&VTs[r * VLD + c] = *(const uint4*)&vtb[(size_t)r * 512 + kt * 64 + c];
        }
        __syncthreads();

        const bool need_mask = (kt >= 2 * qtb);

#pragma unroll
        for (int qg = 0; qg < 2; ++qg) {
            // S^T (M=64 keys, N=16 queries, K=128): 16 MFMA
            f32x4 sacc[4];
#pragma unroll
            for (int mt = 0; mt < 4; ++mt) sacc[mt] = (f32x4){0.f, 0.f, 0.f, 0.f};
#pragma unroll
            for (int mt = 0; mt < 4; ++mt)
#pragma unroll
                for (int kc = 0; kc < 4; ++kc) {
                    bf16x8 af = *(const bf16x8*)&Ks[(mt * 16 + qcol) * KLD + kc * 32 + quad * 8];
                    sacc[mt] = __builtin_amdgcn_mfma_f32_16x16x32_bf16(af, qfrag[qg][kc], sacc[mt], 0, 0, 0);
                }

            float s[16];
#pragma unroll
            for (int mt = 0; mt < 4; ++mt)
#pragma unroll
                for (int r = 0; r < 4; ++r)
                    s[mt * 4 + r] = sacc[mt][r] * scale;
            if (need_mask) {
                const int qglob = qtb * 128 + w * 32 + qg * 16 + qcol;
#pragma unroll
                for (int mt = 0; mt < 4; ++mt)
#pragma unroll
                    for (int r = 0; r < 4; ++r)
                        if (kt * 64 + mt * 16 + quad * 4 + r > qglob)
                            s[mt * 4 + r] = -1e30f;
            }

            float mx = s[0];
#pragma unroll
            for (int i = 1; i < 16; ++i) mx = fmaxf(mx, s[i]);
            mx = fmaxf(mx, __shfl_xor(mx, 16));
            mx = fmaxf(mx, __shfl_xor(mx, 32));
            const float m_new = fmaxf(m_run[qg], mx);
            const float alpha = __expf(m_run[qg] - m_new);   // first iter: exp(-inf)=0
            float p16[16];
            float sum = 0.f;
#pragma unroll
            for (int i = 0; i < 16; ++i) { p16[i] = __expf(s[i] - m_new); sum += p16[i]; }
            sum += __shfl_xor(sum, 16);
            sum += __shfl_xor(sum, 32);
            l_run[qg] = l_run[qg] * alpha + sum;
            m_run[qg] = m_new;
            if (quad == 0) aS[w][qg][qcol] = alpha;

            // P -> wave-private LDS rows [w*32 + qg*16, +16)
#pragma unroll
            for (int mt = 0; mt < 4; ++mt) {
                bf16x4 pb = {(bf16_t)p16[mt * 4 + 0], (bf16_t)p16[mt * 4 + 1],
                             (bf16_t)p16[mt * 4 + 2], (bf16_t)p16[mt * 4 + 3]};
                *(bf16x4*)&Ps[(w * 32 + qg * 16 + qcol) * PLD + mt * 16 + quad * 4] = pb;
            }

            // rescale O rows (query = quad*4 + r within qg) by alpha
            f32x4 alpha4 = *(const f32x4*)&aS[w][qg][quad * 4];
#pragma unroll
            for (int nt = 0; nt < 8; ++nt)
#pragma unroll
                for (int r = 0; r < 4; ++r)
                    acc_o[qg][nt][r] *= alpha4[r];

            // O += P·V (M=16 queries, N=128 dims, K=64 keys): 16 MFMA
#pragma unroll
            for (int kc2 = 0; kc2 < 2; ++kc2) {
                bf16x8 pf = *(const bf16x8*)&Ps[(w * 32 + qg * 16 + qcol) * PLD + kc2 * 32 + quad * 8];
#pragma unroll
                for (int nt = 0; nt < 8; ++nt) {
                    bf16x8 vf = *(const bf16x8*)&VTs[(nt * 16 + qcol) * VLD + kc2 * 32 + quad * 8];
                    acc_o[qg][nt] = __builtin_amdgcn_mfma_f32_16x16x32_bf16(pf, vf, acc_o[qg][nt], 0, 0, 0);
                }
            }
        }
    }

    // epilogue: y[(b, t, h*128 + d)] = O / l
    if (quad == 0) { lS[w][0][qcol] = l_run[0]; lS[w][1][qcol] = l_run[1]; }
#pragma unroll
    for (int qg = 0; qg < 2; ++qg) {
        f32x4 l4 = *(const f32x4*)&lS[w][qg][quad * 4];
#pragma unroll
        for (int nt = 0; nt < 8; ++nt)
#pragma unroll
            for (int r = 0; r < 4; ++r) {
                const int t  = qtb * 128 + w * 32 + qg * 16 + quad * 4 + r;
                const int cc = h * 128 + nt * 16 + qcol;
                y[(size_t)(b * 512 + t) * 2048 + cc] = (bf16_t)(acc_o[qg][nt][r] / l4[r]);
            }
    }
}

// ---------------------------------------------------------------------------
extern "C" void kernel_launch(void* const* d_in, const int* in_sizes, int n_in,
                              void* d_out, int out_size, void* d_ws, size_t ws_size,
                              hipStream_t stream)
{
    (void)in_sizes; (void)n_in; (void)out_size; (void)ws_size;

    const float* x    = (const float*)d_in[0];   // (8, 512, 2048) fp32
    const float* Wqkv = (const float*)d_in[1];   // (6144, 2048)  fp32
    const float* Wout = (const float*)d_in[2];   // (2048, 2048)  fp32
    float* out = (float*)d_out;                  // (8, 512, 2048) fp32

    const size_t SEG = (size_t)8 * 16 * 512 * 128;   // 8,388,608 elems (16 MB bf16)
    bf16_t* q      = (bf16_t*)d_ws;          // [0, 16 MB)
    bf16_t* k      = q + SEG;                // [16, 32)
    bf16_t* vT     = k + SEG;                // [32, 48)   (B,H,hd,T)
    bf16_t* xb     = vT + SEG;               // [48, 64)   bf16 x — dead after GEMM1
    bf16_t* y      = xb;                     //            y aliases xb
    bf16_t* Wqkvb  = xb + SEG;               // [64, 88)   bf16 Wqkv
    bf16_t* Woutb  = Wqkvb + (size_t)6144 * 2048;   // [88, 96)

    f32_to_bf16<<<(8388608 / 8) / 256, 256, 0, stream>>>(x, xb, 8388608 / 8);
    f32_to_bf16<<<(12582912 / 8) / 256, 256, 0, stream>>>(Wqkv, Wqkvb, 12582912 / 8);
    f32_to_bf16<<<(4194304 / 8) / 256, 256, 0, stream>>>(Wout, Woutb, 4194304 / 8);
    gemm256<0><<<dim3(4096 / 256, 6144 / 256), 512, 0, stream>>>(xb, Wqkvb, 2048, q, k, vT, nullptr);
    rope_kernel<<<(2 * 128 * 512 * 8) / 256, 256, 0, stream>>>(q, k);
    flash_attn<<<dim3(4, 16, 8), 256, 0, stream>>>(q, k, vT, y);
    gemm256<1><<<dim3(4096 / 256, 2048 / 256), 512, 0, stream>>>(y, Woutb, 2048, nullptr, nullptr, nullptr, out);
}